// Round 12
// baseline (187.201 us; speedup 1.0000x reference)
//
#include <hip/hip_runtime.h>

typedef float f32x2 __attribute__((ext_vector_type(2)));

#define LOG2E 1.44269504088896340736f
#define LN2   0.69314718055994530942f
#define S_    8192
#define WSTEP 512           // steps per wave (independent, self-staging)
#define NCH   16            // waves per sequence
#define TPB   256
#define NWAVE 4             // waves per block; no cross-wave sync

#if __has_builtin(__builtin_amdgcn_exp2f)
__device__ __forceinline__ float exp2f_(float x){ return __builtin_amdgcn_exp2f(x); }
#else
__device__ __forceinline__ float exp2f_(float x){ return __expf(x * LN2); }
#endif
#if __has_builtin(__builtin_amdgcn_logf)
__device__ __forceinline__ float log2f_(float x){ return __builtin_amdgcn_logf(x); }
#else
__device__ __forceinline__ float log2f_(float x){ return __logf(x) * LOG2E; }
#endif

__device__ __forceinline__ void gload16(const void* g, void* l){
#if __has_builtin(__builtin_amdgcn_global_load_lds)
    __builtin_amdgcn_global_load_lds((const __attribute__((address_space(1))) void*)g,
                                     (__attribute__((address_space(3))) void*)l, 16, 0, 0);
#endif
}

// ---- packed 3x3 column state: L[j] = (V[0][j],V[1][j]), H[j] = V[2][j] ----
#define RNORM(L0,L1,L2,H0,H1,H2,S2) { \
    f32x2 _m2 = __builtin_elementwise_max(__builtin_elementwise_max(L0,L1),L2); \
    float _m  = fmaxf(fmaxf(_m2.x,_m2.y), fmaxf(fmaxf(H0,H1),H2)); \
    int _e = (__float_as_int(_m) >> 23) & 0xff; \
    float _rs = __int_as_float((254 - _e) << 23); \
    L0*=_rs; L1*=_rs; L2*=_rs; H0*=_rs; H1*=_rs; H2*=_rs; \
    S2 += (float)(_e - 127); }

#define STEPM(L0,L1,L2,H0,H1,H2, ea,eb,ec) { \
    float _E0=__expf(ea), _E1=__expf(eb), _E2=__expf(ec); \
    f32x2 _n0=(L0*W00+L1*W10+L2*W20)*_E0; float _q0=(H0*W00+H1*W10+H2*W20)*_E0; \
    f32x2 _n1=(L0*W01+L1*W11+L2*W21)*_E1; float _q1=(H0*W01+H1*W11+H2*W21)*_E1; \
    f32x2 _n2=(L0*W02+L1*W12+L2*W22)*_E2; float _q2=(H0*W02+H1*W12+H2*W22)*_E2; \
    L0=_n0; L1=_n1; L2=_n2; H0=_q0; H1=_q1; H2=_q2; }

#define COMBINE(AL0,AL1,AL2,AH0,AH1,AH2, BL0,BL1,BL2,BH0,BH1,BH2) { \
    f32x2 _c0 = AL0*BL0.x + AL1*BL0.y + AL2*BH0; \
    float _d0 = AH0*BL0.x + AH1*BL0.y + AH2*BH0; \
    f32x2 _c1 = AL0*BL1.x + AL1*BL1.y + AL2*BH1; \
    float _d1 = AH0*BL1.x + AH1*BL1.y + AH2*BH1; \
    f32x2 _c2 = AL0*BL2.x + AL1*BL2.y + AL2*BH2; \
    float _d2 = AH0*BL2.x + AH1*BL2.y + AH2*BH2; \
    AL0=_c0; AL1=_c1; AL2=_c2; AH0=_d0; AH1=_d1; AH2=_d2; }

__device__ __forceinline__ void mul33(float* C, const float* A, const float* B){
#pragma unroll
    for (int i=0;i<3;i++){
        float a0=A[i*3], a1=A[i*3+1], a2=A[i*3+2];
#pragma unroll
        for (int j=0;j<3;j++)
            C[i*3+j] = a0*B[j] + a1*B[3+j] + a2*B[6+j];
    }
}
__device__ __forceinline__ void renorm9(float* V, float& s){
    float m = fmaxf(fmaxf(fmaxf(V[0],V[1]),fmaxf(V[2],V[3])),
                    fmaxf(fmaxf(V[4],V[5]),fmaxf(V[6],V[7])));
    m = fmaxf(m, V[8]);
    int e = (__float_as_int(m) >> 23) & 0xff;
    float rs = __int_as_float((254 - e) << 23);
#pragma unroll
    for (int k=0;k<9;++k) V[k] *= rs;
    s += (float)(e - 127);
}

// Wave g = blockIdx*4+wv owns steps [h*512,(h+1)*512) of sequence b (g=b*16+h).
// Self-staging: 6 coalesced global_load_lds into the wave's OWN 6KB LDS region
// (XOR-swizzled source so b128 reads are ~4-way instead of 16-way) — no
// __syncthreads, just s_waitcnt vmcnt(0). Lane l folds steps 8l..8l+7 as two
// 4-step chains (ILP), combines, then one ordered 64-lane shfl tree.
// Record (16 floats @ ws[g*16]): V row-major[9], S2, score, e0[3], pad[2].
extern "C" __global__ __launch_bounds__(TPB)
void crf_fwd(const float* __restrict__ em, const int* __restrict__ lab,
             const float* __restrict__ stt, const float* __restrict__ trt,
             const float* __restrict__ ent, float* __restrict__ ws)
{
    const int wv = threadIdx.x >> 6, ln = threadIdx.x & 63;
    const int g = blockIdx.x*NWAVE + wv;
    const int b = g >> 4, h = g & 15;

    __shared__ float4 emS[NWAVE*384];      // 4 waves x 6KB = 24KB
    float4* myS = emS + wv*384;            // wave-private region

    const float* emB = em + ((size_t)b*S_ + (size_t)h*WSTEP)*3;
    const int*   lbB = lab + (size_t)b*S_ + h*WSTEP;

    // ---- stage own 6KB, coalesced, source-swizzled (involution u^=(u>>3)&7) ----
    {
        const char* gb = (const char*)emB;
        char* lb = (char*)myS;
        const int ksw = ln ^ ((ln >> 3) & 7);    // permutes within each 1KB group
#pragma unroll
        for (int i=0;i<6;++i)
            gload16(gb + (size_t)(i*64 + ksw)*16, lb + i*1024);
    }

    // ---- labels: 2 coalesced int4 per lane (steps 8l..8l+7) ----
    const int4* lb4 = (const int4*)lbB;
    int4 lv0 = lb4[2*ln], lv1 = lb4[2*ln+1];

    // wave-uniform linear-domain transition weights (scalar path, overlaps loads)
    float W00=__expf(trt[0]), W01=__expf(trt[1]), W02=__expf(trt[2]);
    float W10=__expf(trt[3]), W11=__expf(trt[4]), W12=__expf(trt[5]);
    float W20=__expf(trt[6]), W21=__expf(trt[7]), W22=__expf(trt[8]);
    float tT[9] = {trt[0],trt[1],trt[2],trt[3],trt[4],trt[5],trt[6],trt[7],trt[8]};
    float st0=stt[0], st1=stt[1], st2=stt[2];

    // prev-label seam
    const bool head = (h==0 && ln==0);
    int prevA = __shfl_up(lv1.w, 1, 64);
    if (ln == 0) prevA = (h == 0) ? 0 : lbB[-1];
    int prevB = lv0.w;                      // label of step 3 (chain B starts at 4)

    // ---- wait for own staging + labels (wave-private: no barrier needed) ----
    asm volatile("s_waitcnt vmcnt(0)" ::: "memory");
    __builtin_amdgcn_sched_barrier(0);

    // ---- read own 8 steps: 6 swizzled ds_read_b128 (~4-way) ----
    float ew[24];
    {
        const int v0 = 6*ln;
#pragma unroll
        for (int r=0;r<6;++r){
            int v = v0 + r;
            int u = v ^ ((v >> 3) & 7);
            *(float4*)&ew[4*r] = myS[u];
        }
    }

    // ---- two 4-step chains (A: steps 0-3, B: steps 4-7), packed-column math ----
    f32x2 AL0={1,0}, AL1={0,1}, AL2={0,0};  float AH0=0, AH1=0, AH2=1;
    f32x2 BL0={1,0}, BL1={0,1}, BL2={0,0};  float BH0=0, BH1=0, BH2=1;
    float S2 = 0.f, sc = 0.f;
    int la[4] = {lv0.x, lv0.y, lv0.z, lv0.w};
    int lb_[4] = {lv1.x, lv1.y, lv1.z, lv1.w};

#pragma unroll
    for (int s=0; s<4; ++s){
        // chain A
        {
            float ea=ew[3*s], eb=ew[3*s+1], ec=ew[3*s+2];
            int l = la[s];
            float ee = (l==1) ? eb : ((l==2) ? ec : ea);
            if (head && s==0){
                float sv = (l==1) ? st1 : ((l==2) ? st2 : st0);
                sc += sv + ee;
            } else {
                sc += tT[prevA*3+l] + ee;
            }
            prevA = l;
            if (!(head && s==0)) STEPM(AL0,AL1,AL2,AH0,AH1,AH2, ea,eb,ec);
        }
        // chain B (steps 4-7)
        {
            float ea=ew[12+3*s], eb=ew[12+3*s+1], ec=ew[12+3*s+2];
            int l = lb_[s];
            float ee = (l==1) ? eb : ((l==2) ? ec : ea);
            sc += tT[prevB*3+l] + ee;
            prevB = l;
            STEPM(BL0,BL1,BL2,BH0,BH1,BH2, ea,eb,ec);
        }
    }
    RNORM(AL0,AL1,AL2,AH0,AH1,AH2, S2);
    RNORM(BL0,BL1,BL2,BH0,BH1,BH2, S2);
    COMBINE(AL0,AL1,AL2,AH0,AH1,AH2, BL0,BL1,BL2,BH0,BH1,BH2);
    RNORM(AL0,AL1,AL2,AH0,AH1,AH2, S2);

    // ---- ordered 64-lane tree: lane i := chunk_i * chunk_{i+off} ----
#pragma unroll
    for (int off=1; off<64; off<<=1){
        f32x2 bL0, bL1, bL2; float bH0, bH1, bH2, bS2;
        bL0.x=__shfl_down(AL0.x,(unsigned)off,64); bL0.y=__shfl_down(AL0.y,(unsigned)off,64);
        bL1.x=__shfl_down(AL1.x,(unsigned)off,64); bL1.y=__shfl_down(AL1.y,(unsigned)off,64);
        bL2.x=__shfl_down(AL2.x,(unsigned)off,64); bL2.y=__shfl_down(AL2.y,(unsigned)off,64);
        bH0=__shfl_down(AH0,(unsigned)off,64); bH1=__shfl_down(AH1,(unsigned)off,64);
        bH2=__shfl_down(AH2,(unsigned)off,64); bS2=__shfl_down(S2,(unsigned)off,64);
        COMBINE(AL0,AL1,AL2,AH0,AH1,AH2, bL0,bL1,bL2,bH0,bH1,bH2);
        S2 += bS2;
        RNORM(AL0,AL1,AL2,AH0,AH1,AH2, S2);
    }
#pragma unroll
    for (int off=32; off; off>>=1) sc += __shfl_down(sc, (unsigned)off, 64);

    if (ln == 0){
        float4* r = (float4*)(ws + (size_t)g*16);
        r[0] = make_float4(AL0.x, AL1.x, AL2.x, AL0.y);
        r[1] = make_float4(AL1.y, AL2.y, AH0,   AH1);
        r[2] = make_float4(AH2,   S2,    sc,    ew[0]);
        r[3] = make_float4(ew[1], ew[2], 0.f,   0.f);
    }
}

// stage 1: one thread per sequence chains 16 records; alpha0 + end fold; partials
extern "C" __global__ __launch_bounds__(64)
void crf_fin1(const float* __restrict__ ws, const float* __restrict__ stt,
              const float* __restrict__ ent, float* __restrict__ partial)
{
    const int q = blockIdx.x*64 + threadIdx.x;   // sequence id
    const float* rr = ws + (size_t)q*NCH*16;
    float C[9], S = rr[9], sc = rr[10];
#pragma unroll
    for (int k=0;k<9;++k) C[k]=rr[k];
#pragma unroll
    for (int p=1;p<NCH;++p){
        const float* r = rr + p*16;
        float T[9]; mul33(T, C, r);
        S += r[9]; sc += r[10];
        renorm9(T, S);
#pragma unroll
        for (int k=0;k<9;++k) C[k]=T[k];
    }
    float a0=(stt[0]+rr[11])*LOG2E, a1=(stt[1]+rr[12])*LOG2E, a2=(stt[2]+rr[13])*LOG2E;
    float am = fmaxf(fmaxf(a0,a1),a2);
    float w0=exp2f_(a0-am), w1=exp2f_(a1-am), w2=exp2f_(a2-am);
    float q0=w0*C[0]+w1*C[3]+w2*C[6];
    float q1=w0*C[1]+w1*C[4]+w2*C[7];
    float q2=w0*C[2]+w1*C[5]+w2*C[8];
    float z = q0*exp2f_(ent[0]*LOG2E) + q1*exp2f_(ent[1]*LOG2E) + q2*exp2f_(ent[2]*LOG2E);
    float logz = (am + S + log2f_(z)) * LN2;
    float nll = logz - sc;
#pragma unroll
    for (int off=32; off; off>>=1) nll += __shfl_down(nll, (unsigned)off, 64);
    if (threadIdx.x==0) partial[blockIdx.x] = nll;
}

extern "C" __global__ __launch_bounds__(64)
void crf_fin2(const float* __restrict__ partial, float* __restrict__ out)
{
    float v = (threadIdx.x < 16) ? partial[threadIdx.x] : 0.f;
#pragma unroll
    for (int off=32; off; off>>=1) v += __shfl_down(v, (unsigned)off, 64);
    if (threadIdx.x==0) out[0] = v;
}

extern "C" void kernel_launch(void* const* d_in, const int* in_sizes, int n_in,
                              void* d_out, int out_size, void* d_ws, size_t ws_size,
                              hipStream_t stream) {
    const float* em  = (const float*)d_in[0];
    const int*   lab = (const int*)d_in[1];
    const float* stt = (const float*)d_in[2];
    const float* trt = (const float*)d_in[3];
    const float* ent = (const float*)d_in[4];
    float* out = (float*)d_out;
    float* ws  = (float*)d_ws;                 // 16*B*16 floats = 1 MB records
    const int B = in_sizes[1] / S_;            // 1024
    float* partial = ws + (size_t)NCH*B*16;

    crf_fwd<<<B*NCH/NWAVE, TPB, 0, stream>>>(em, lab, stt, trt, ent, ws);
    crf_fin1<<<B/64, 64, 0, stream>>>(ws, stt, ent, partial);
    crf_fin2<<<1, 64, 0, stream>>>(partial, out);
}